// Round 9
// baseline (731.689 us; speedup 1.0000x reference)
//
#include <hip/hip_runtime.h>
#include <math.h>

#define NB 2048        // batches
#define NS 256         // samples per batch
#define ND 128         // features
#define NCOL 129       // ND+1 (ones column)
#define LDA 132        // padded LDS row stride (floats)
#define TS 32          // samples per formation chunk (= one MFMA K step)
#define XTP 40         // XT pitch in shorts (32 samples + 8 pad -> 2-way banks)
#define BSTRIDE 132    // Beta row stride in workspace (floats)
#define STDDEV 0.1f

typedef __attribute__((ext_vector_type(8))) short bf16x8;
typedef __attribute__((ext_vector_type(4))) float f32x4;

__device__ inline unsigned short f32_to_bf16_rn(float f) {
  unsigned int u = __float_as_uint(f);
  unsigned int r = (u + 0x7FFFu + ((u >> 16) & 1u)) >> 16;
  return (unsigned short)r;
}
__device__ inline float bf16u_to_f32(unsigned short h) {
  return __uint_as_float(((unsigned int)h) << 16);
}
// wave-uniform lane read: v_readlane (no LDS-pipe traffic)
__device__ inline float rdlane(float v, int lane) {
  return __int_as_float(__builtin_amdgcn_readlane(__float_as_int(v), lane));
}

// 64 named elimination scalars: a<i>_<j>, row R_i = ty*8+i, cols
// C_j = tx*4+j (j<4) and 64+tx*4+(j-4) (j>=4).  Named scalars (not an
// array) so they can NEVER be demoted to scratch (rounds 2/3: acc[8][8]
// went to localMem -> 7-16 GB HBM scratch traffic).
#define FOR_ROW(F, i) F(i,0) F(i,1) F(i,2) F(i,3) F(i,4) F(i,5) F(i,6) F(i,7)
#define FOR_ALL(F) FOR_ROW(F,0) FOR_ROW(F,1) FOR_ROW(F,2) FOR_ROW(F,3) \
                   FOR_ROW(F,4) FOR_ROW(F,5) FOR_ROW(F,6) FOR_ROW(F,7)

#define ACC_DECL(i,j) float a##i##_##j = 0.f;
#define ACC_UPD(i,j)  a##i##_##j = fmaf(-m##i, rc##j, a##i##_##j);

// row cc -= m * row c (own 8 cols in registers)
#define ACC8(cc, c, m) \
  a##cc##_0 = fmaf(-(m), a##c##_0, a##cc##_0); \
  a##cc##_1 = fmaf(-(m), a##c##_1, a##cc##_1); \
  a##cc##_2 = fmaf(-(m), a##c##_2, a##cc##_2); \
  a##cc##_3 = fmaf(-(m), a##c##_3, a##cc##_3); \
  a##cc##_4 = fmaf(-(m), a##c##_4, a##cc##_4); \
  a##cc##_5 = fmaf(-(m), a##c##_5, a##cc##_5); \
  a##cc##_6 = fmaf(-(m), a##c##_6, a##cc##_6); \
  a##cc##_7 = fmaf(-(m), a##c##_7, a##cc##_7);

#define PF_U(c, cc) { const float m_ = pv##cc * pinv; \
  ACC8(cc, c, m_) \
  rh##cc = fmaf(-m_, rh##c, rh##cc); \
  bc##cc = fmaf(-m_, bc##c, bc##cc); }

#define PF_STEP(c, J0, J1, J2, J3, UPDS) { \
  const float pv0 = rdlane(a##c##_##J0, lsrc0); \
  const float pv1 = rdlane(a##c##_##J1, lsrc0); \
  const float pv2 = rdlane(a##c##_##J2, lsrc0); \
  const float pv3 = rdlane(a##c##_##J3, lsrc0); \
  const float pv4 = rdlane(a##c##_##J0, lsrc1); \
  const float pv5 = rdlane(a##c##_##J1, lsrc1); \
  const float pv6 = rdlane(a##c##_##J2, lsrc1); \
  const float pv7 = rdlane(a##c##_##J3, lsrc1); \
  const float pinv = 1.0f / pv##c; \
  if (tx == 3) pdiag[p8 + (c)] = pinv; \
  const float mb_ = bc##c * pinv; \
  cornb = fmaf(-mb_, bc##c, cornb); \
  cornr = fmaf(-mb_, rh##c, cornr); \
  UPDS }

#define PUBROW(c) \
  *(float4*)&rbp[(c) * LDA + txc0] = make_float4(a##c##_0, a##c##_1, a##c##_2, a##c##_3); \
  *(float4*)&rbp[(c) * LDA + txc1] = make_float4(a##c##_4, a##c##_5, a##c##_6, a##c##_7);

#define TRAIL_C(c) { \
  const float4 o0_ = *(const float4*)&rbp[(c) * LDA + ty8]; \
  const float4 o1_ = *(const float4*)&rbp[(c) * LDA + ty8 + 4]; \
  const float4 c0_ = *(const float4*)&rbp[(c) * LDA + txc0]; \
  const float4 c1_ = *(const float4*)&rbp[(c) * LDA + txc1]; \
  const float pk_ = pd[(c)]; \
  const float m0 = o0_.x*pk_, m1 = o0_.y*pk_, m2 = o0_.z*pk_, m3 = o0_.w*pk_; \
  const float m4 = o1_.x*pk_, m5 = o1_.y*pk_, m6 = o1_.z*pk_, m7 = o1_.w*pk_; \
  const float rc0 = c0_.x, rc1 = c0_.y, rc2 = c0_.z, rc3 = c0_.w; \
  const float rc4 = c1_.x, rc5 = c1_.y, rc6 = c1_.z, rc7 = c1_.w; \
  FOR_ALL(ACC_UPD) \
  hr0 = fmaf(m0, rp[(c)], hr0); hr1 = fmaf(m1, rp[(c)], hr1); \
  hr2 = fmaf(m2, rp[(c)], hr2); hr3 = fmaf(m3, rp[(c)], hr3); \
  hr4 = fmaf(m4, rp[(c)], hr4); hr5 = fmaf(m5, rp[(c)], hr5); \
  hr6 = fmaf(m6, rp[(c)], hr6); hr7 = fmaf(m7, rp[(c)], hr7); \
  hb0 = fmaf(m0, bp[(c)], hb0); hb1 = fmaf(m1, bp[(c)], hb1); \
  hb2 = fmaf(m2, bp[(c)], hb2); hb3 = fmaf(m3, bp[(c)], hb3); \
  hb4 = fmaf(m4, bp[(c)], hb4); hb5 = fmaf(m5, bp[(c)], hb5); \
  hb6 = fmaf(m6, bp[(c)], hb6); hb7 = fmaf(m7, bp[(c)], hb7); }

#define PC_U(cc, J, SRC, bev) { const float u_ = rdlane(a##cc##_##J, SRC); \
  rh##cc = fmaf(-u_, bev, rh##cc); }
#define PC_S(c, UPDS) { be##c = rh##c * pd##c; UPDS }

#define PCT_ROW(i) const float ps##i = hi \
  ? fmaf(a##i##_4, be0, fmaf(a##i##_5, be1, fmaf(a##i##_6, be2, a##i##_7 * be3))) \
  : fmaf(a##i##_0, be0, fmaf(a##i##_1, be1, fmaf(a##i##_2, be2, a##i##_3 * be3)));

// ---- MFMA formation macros ----
#define FOR_J(F) F(0) F(1) F(2) F(3) F(4) F(5) F(6) F(7)
#define CB_DECL(j) f32x4 cb0_##j = {0.f,0.f,0.f,0.f}; f32x4 cb1_##j = {0.f,0.f,0.f,0.f};

#define MF_J(j) { \
  const bf16x8 Bh = *(const bf16x8*)&XTh[(16*(j) + tx)*XTP + kq]; \
  const bf16x8 Bl = *(const bf16x8*)&XTl[(16*(j) + tx)*XTP + kq]; \
  cb0_##j = __builtin_amdgcn_mfma_f32_16x16x32_bf16(Ah0, Bh, cb0_##j, 0,0,0); \
  cb0_##j = __builtin_amdgcn_mfma_f32_16x16x32_bf16(Ah0, Bl, cb0_##j, 0,0,0); \
  cb0_##j = __builtin_amdgcn_mfma_f32_16x16x32_bf16(Al0, Bh, cb0_##j, 0,0,0); \
  cb1_##j = __builtin_amdgcn_mfma_f32_16x16x32_bf16(Ah1, Bh, cb1_##j, 0,0,0); \
  cb1_##j = __builtin_amdgcn_mfma_f32_16x16x32_bf16(Ah1, Bl, cb1_##j, 0,0,0); \
  cb1_##j = __builtin_amdgcn_mfma_f32_16x16x32_bf16(Al1, Bh, cb1_##j, 0,0,0); }

// transpose-convert one sample u (literal) of column d into frag vectors
#define TCONV(u, HV, LV, e) { \
  const float xf_ = sA[(sh + (u)) * LDA + d]; \
  const unsigned short hh_ = f32_to_bf16_rn(xf_); \
  const float hf_ = bf16u_to_f32(hh_); \
  const unsigned short ll_ = f32_to_bf16_rn(xf_ - hf_); \
  HV[e] = (short)hh_; LV[e] = (short)ll_; }

// stage one quarter of the chunk from prefetch register nv
#define STAGE_IT(it, nv) { \
  const int idx_ = t + (it) * 256; \
  const int s_ = idx_ >> 5, d4_ = idx_ & 31; \
  const float4 xq_ = *(const float4*)&xv[d4_ * 4]; \
  float4 xl_; \
  xl_.x = xq_.x + STDDEV * nv.x; \
  xl_.y = xq_.y + STDDEV * nv.y; \
  xl_.z = xq_.z + STDDEV * nv.z; \
  xl_.w = xq_.w + STDDEV * nv.w; \
  *(float4*)&sA[s_ * LDA + d4_ * 4] = xl_; }

// bridge: wave-local band write (C frag layout) / read (elimination layout)
#define BW_BJ(b, j) \
  myband[(16*(b) + q4 + 0)*132 + 16*(j) + tx] = cb##b##_##j[0]; \
  myband[(16*(b) + q4 + 1)*132 + 16*(j) + tx] = cb##b##_##j[1]; \
  myband[(16*(b) + q4 + 2)*132 + 16*(j) + tx] = cb##b##_##j[2]; \
  myband[(16*(b) + q4 + 3)*132 + 16*(j) + tx] = cb##b##_##j[3];
#define BW_ALL \
  BW_BJ(0,0) BW_BJ(0,1) BW_BJ(0,2) BW_BJ(0,3) BW_BJ(0,4) BW_BJ(0,5) BW_BJ(0,6) BW_BJ(0,7) \
  BW_BJ(1,0) BW_BJ(1,1) BW_BJ(1,2) BW_BJ(1,3) BW_BJ(1,4) BW_BJ(1,5) BW_BJ(1,6) BW_BJ(1,7)
#define BR_ROW(i) { \
  const float4 lo_ = *(const float4*)&myband[(q8 + (i))*132 + txc0]; \
  const float4 hi_ = *(const float4*)&myband[(q8 + (i))*132 + txc1]; \
  a##i##_0 = lo_.x; a##i##_1 = lo_.y; a##i##_2 = lo_.z; a##i##_3 = lo_.w; \
  a##i##_4 = hi_.x; a##i##_5 = hi_.y; a##i##_6 = hi_.z; a##i##_7 = hi_.w; }
#define BR_ALL \
  BR_ROW(0) BR_ROW(1) BR_ROW(2) BR_ROW(3) BR_ROW(4) BR_ROW(5) BR_ROW(6) BR_ROW(7)

// launch_bounds(256,3): target <=170 unified VGPR+AGPR regs -> 3 blocks/CU
// (round-8 residency cap was 124 VGPR + 64 AGPR = 188 -> 2 waves/EU).
// Tripwire: if WRITE_SIZE balloons, this spilled -- revert to (256,2).
__global__ __launch_bounds__(256, 3)
void k_fit(const float* __restrict__ x, const float* __restrict__ noise,
           const float* __restrict__ W, const float* __restrict__ bptr,
           float* __restrict__ Beta) {
  // region0: phase A = sA f32 [32][132] | XTh u16 [128][40] | XTl u16 [128][40]
  //          bridge  = 2 bands f32 [32][132] (aliased, wave-pair serialized)
  //          phase B = rbuf (2112 f, aliased; region0 dead after bridge)
  //          phase C = sp0/sp1 (256 f, aliased, disjoint from rbuf)
  __shared__ __align__(16) float region0[9344];
  __shared__ __align__(16) float pdiag[NCOL + 3];
  __shared__ __align__(16) float bcol[NCOL + 3];     // border col; [128]=corner
  __shared__ __align__(16) float rhs[NCOL + 3];
  __shared__ __align__(16) float betaL[NCOL + 3];
  __shared__ __align__(16) float yt[TS];
  __shared__ __align__(16) float Wl[128];
  __shared__ __align__(16) float xv[128];

  float* sA = region0;                                   // 4224 floats
  unsigned short* XTh = (unsigned short*)(region0 + 4224);   // 5120 shorts
  unsigned short* XTl = (unsigned short*)(region0 + 4224 + 2560);
  float* band = region0;                                 // bridge alias
  float* rbuf = region0;                                 // phase-B alias [0,2112)
  float* sp0  = region0 + 2112;                          // phase-C alias
  float* sp1  = region0 + 2240;

  const int t  = threadIdx.x;
  const int b  = blockIdx.x;
  const int tx = t & 15;
  const int ty = t >> 4;
  const int wv = t >> 6;          // wave id 0..3
  const int txc0 = tx * 4;
  const int txc1 = 64 + tx * 4;
  const int ty8 = ty * 8;
  const int q4 = 4 * (ty & 3);    // C-frag row group
  const int q8 = 8 * (ty & 3);    // elimination band row base
  const int kq = 8 * (ty & 3);    // K offset within chunk (shorts)
  const float bscal = bptr[0];

  if (t < 128) { Wl[t] = W[t]; xv[t] = x[(size_t)b * ND + t]; }

  FOR_J(CB_DECL)                  // 16 named f32x4 MFMA accumulators
  float col_acc = 0.f, xty_acc = 0.f;

  const float* nbase = noise + (size_t)b * (NS * ND);

  // prefetch chunk 0 (T14: loads in flight across the staging barrier)
  float4 nv0, nv1, nv2, nv3;
  {
    const float4* src = (const float4*)nbase;
    nv0 = src[t]; nv1 = src[t + 256]; nv2 = src[t + 512]; nv3 = src[t + 768];
  }

  // ---------------- phase A: MFMA formation (8 chunks of 32) ----------------
  for (int s0 = 0; s0 < NS; s0 += TS) {
    __syncthreads();  // staging buffers free (covers Wl/xv on first iter)
    {   // write prefetched chunk -> sA (f32), xl = x + 0.1*noise
      STAGE_IT(0, nv0) STAGE_IT(1, nv1) STAGE_IT(2, nv2) STAGE_IT(3, nv3)
      if (t < TS) sA[t * LDA + ND] = 1.0f;   // ones column
    }
    if (s0 + TS < NS) {  // issue next chunk's loads; latency hides under chunk
      const float4* src = (const float4*)(nbase + (size_t)(s0 + TS) * ND);
      nv0 = src[t]; nv1 = src[t + 256]; nv2 = src[t + 512]; nv3 = src[t + 768];
    }
    __syncthreads();
    {   // transpose-convert: feature d = t>>1, sample half (t&1)*16 -> XT h/l
      const int d = t >> 1;
      const int sh = (t & 1) * 16;
      bf16x8 h0, h1, l0, l1;
      TCONV(0,h0,l0,0) TCONV(1,h0,l0,1) TCONV(2,h0,l0,2) TCONV(3,h0,l0,3)
      TCONV(4,h0,l0,4) TCONV(5,h0,l0,5) TCONV(6,h0,l0,6) TCONV(7,h0,l0,7)
      TCONV(8,h1,l1,0) TCONV(9,h1,l1,1) TCONV(10,h1,l1,2) TCONV(11,h1,l1,3)
      TCONV(12,h1,l1,4) TCONV(13,h1,l1,5) TCONV(14,h1,l1,6) TCONV(15,h1,l1,7)
      *(bf16x8*)&XTh[d * XTP + sh]     = h0;
      *(bf16x8*)&XTh[d * XTP + sh + 8] = h1;
      *(bf16x8*)&XTl[d * XTP + sh]     = l0;
      *(bf16x8*)&XTl[d * XTP + sh + 8] = l1;
    }
    {   // y = sigmoid(xl_feat . W + b), 8 threads/sample (f32-exact from sA)
      int sl = t >> 3, p = t & 7;
      float acw = 0.f;
#pragma unroll
      for (int d = 0; d < 4; ++d) {
        float4 a = *(const float4*)&sA[sl * LDA + p * 16 + d * 4];
        float4 w = *(const float4*)&Wl[p * 16 + d * 4];
        acw += a.x * w.x + a.y * w.y + a.z * w.z + a.w * w.w;
      }
      acw += __shfl_xor(acw, 1);
      acw += __shfl_xor(acw, 2);
      acw += __shfl_xor(acw, 4);
      if (p == 0) yt[sl] = 1.f / (1.f + expf(-(acw + bscal)));
    }
    __syncthreads();
    if (t < NCOL) {   // border col sums + Xty (f32-exact from sA)
      for (int s = 0; s < TS; ++s) {
        float v = sA[s * LDA + t];
        col_acc += v;
        xty_acc += yt[s] * v;
      }
    }
    {   // MFMA: wave wv owns rows 32wv..32wv+31; K = this chunk (32 samples)
      const bf16x8 Ah0 = *(const bf16x8*)&XTh[(32*wv + tx)*XTP + kq];
      const bf16x8 Al0 = *(const bf16x8*)&XTl[(32*wv + tx)*XTP + kq];
      const bf16x8 Ah1 = *(const bf16x8*)&XTh[(32*wv + 16 + tx)*XTP + kq];
      const bf16x8 Al1 = *(const bf16x8*)&XTl[(32*wv + 16 + tx)*XTP + kq];
      MF_J(0) MF_J(1) MF_J(2) MF_J(3) MF_J(4) MF_J(5) MF_J(6) MF_J(7)
    }
  }
  if (t < NCOL) { bcol[t] = col_acc; rhs[t] = xty_acc; }  // corner=256 natural
  __syncthreads();   // all XT reads done; region0 becomes bridge bands

  // ---- bridge: C fragments -> named elimination scalars (intra-wave) ----
  FOR_ALL(ACC_DECL)
  {
    float* myband = band + (wv & 1) * 4224;
    if (wv < 2) {
      BW_ALL
      asm volatile("s_waitcnt lgkmcnt(0)" ::: "memory");
      BR_ALL
      asm volatile("s_waitcnt lgkmcnt(0)" ::: "memory");
    }
    __syncthreads();
    if (wv >= 2) {
      BW_ALL
      asm volatile("s_waitcnt lgkmcnt(0)" ::: "memory");
      BR_ALL
      asm volatile("s_waitcnt lgkmcnt(0)" ::: "memory");
    }
    __syncthreads();   // bridge done; region0 free for rbuf/sp aliases
  }

  // ------- phase B: panel elimination (readlane factorization) --------------
#pragma unroll 1
  for (int p = 0; p < 16; ++p) {
    const int p8 = p * 8;
    const int ol = (p < 8) ? (p << 1) : ((p - 8) << 1);
    float* rbp = &rbuf[(p & 1) * (8 * LDA)];
    if (ty == p) {
      asm volatile("s_waitcnt lgkmcnt(0)" ::: "memory");
      const float4 rq0 = *(const float4*)&rhs[p8];
      const float4 rq1 = *(const float4*)&rhs[p8 + 4];
      const float4 bq0 = *(const float4*)&bcol[p8];
      const float4 bq1 = *(const float4*)&bcol[p8 + 4];
      float rh0 = rq0.x, rh1 = rq0.y, rh2 = rq0.z, rh3 = rq0.w;
      float rh4 = rq1.x, rh5 = rq1.y, rh6 = rq1.z, rh7 = rq1.w;
      float bc0 = bq0.x, bc1 = bq0.y, bc2 = bq0.z, bc3 = bq0.w;
      float bc4 = bq1.x, bc5 = bq1.y, bc6 = bq1.z, bc7 = bq1.w;
      float cornr = rhs[ND], cornb = bcol[ND];
      const int lsrc0 = ((p & 3) << 4) + ol;
      const int lsrc1 = lsrc0 + 1;
      if (p < 8) {
        PF_STEP(0, 0,1,2,3, PF_U(0,1) PF_U(0,2) PF_U(0,3) PF_U(0,4) PF_U(0,5) PF_U(0,6) PF_U(0,7))
        PF_STEP(1, 0,1,2,3, PF_U(1,2) PF_U(1,3) PF_U(1,4) PF_U(1,5) PF_U(1,6) PF_U(1,7))
        PF_STEP(2, 0,1,2,3, PF_U(2,3) PF_U(2,4) PF_U(2,5) PF_U(2,6) PF_U(2,7))
        PF_STEP(3, 0,1,2,3, PF_U(3,4) PF_U(3,5) PF_U(3,6) PF_U(3,7))
        PF_STEP(4, 0,1,2,3, PF_U(4,5) PF_U(4,6) PF_U(4,7))
        PF_STEP(5, 0,1,2,3, PF_U(5,6) PF_U(5,7))
        PF_STEP(6, 0,1,2,3, PF_U(6,7))
        PF_STEP(7, 0,1,2,3, )
      } else {
        PF_STEP(0, 4,5,6,7, PF_U(0,1) PF_U(0,2) PF_U(0,3) PF_U(0,4) PF_U(0,5) PF_U(0,6) PF_U(0,7))
        PF_STEP(1, 4,5,6,7, PF_U(1,2) PF_U(1,3) PF_U(1,4) PF_U(1,5) PF_U(1,6) PF_U(1,7))
        PF_STEP(2, 4,5,6,7, PF_U(2,3) PF_U(2,4) PF_U(2,5) PF_U(2,6) PF_U(2,7))
        PF_STEP(3, 4,5,6,7, PF_U(3,4) PF_U(3,5) PF_U(3,6) PF_U(3,7))
        PF_STEP(4, 4,5,6,7, PF_U(4,5) PF_U(4,6) PF_U(4,7))
        PF_STEP(5, 4,5,6,7, PF_U(5,6) PF_U(5,7))
        PF_STEP(6, 4,5,6,7, PF_U(6,7))
        PF_STEP(7, 4,5,6,7, )
      }
      PUBROW(0) PUBROW(1) PUBROW(2) PUBROW(3)
      PUBROW(4) PUBROW(5) PUBROW(6) PUBROW(7)
      if (tx == 0) {
        *(float4*)&rhs[p8]     = make_float4(rh0, rh1, rh2, rh3);
        *(float4*)&rhs[p8 + 4] = make_float4(rh4, rh5, rh6, rh7);
      }
      if (tx == 1) {
        *(float4*)&bcol[p8]     = make_float4(bc0, bc1, bc2, bc3);
        *(float4*)&bcol[p8 + 4] = make_float4(bc4, bc5, bc6, bc7);
      }
      if (tx == 2) { rhs[ND] = cornr; bcol[ND] = cornb; }
    }
    __syncthreads();
    if (ty > p) {
      const float4 d0_ = *(const float4*)&pdiag[p8];
      const float4 d1_ = *(const float4*)&pdiag[p8 + 4];
      const float4 rq0_ = *(const float4*)&rhs[p8];
      const float4 rq1_ = *(const float4*)&rhs[p8 + 4];
      const float4 bq0_ = *(const float4*)&bcol[p8];
      const float4 bq1_ = *(const float4*)&bcol[p8 + 4];
      const float pd[8] = {d0_.x, d0_.y, d0_.z, d0_.w, d1_.x, d1_.y, d1_.z, d1_.w};
      const float rp[8] = {rq0_.x, rq0_.y, rq0_.z, rq0_.w, rq1_.x, rq1_.y, rq1_.z, rq1_.w};
      const float bp[8] = {bq0_.x, bq0_.y, bq0_.z, bq0_.w, bq1_.x, bq1_.y, bq1_.z, bq1_.w};
      float hr0 = 0.f, hr1 = 0.f, hr2 = 0.f, hr3 = 0.f;
      float hr4 = 0.f, hr5 = 0.f, hr6 = 0.f, hr7 = 0.f;
      float hb0 = 0.f, hb1 = 0.f, hb2 = 0.f, hb3 = 0.f;
      float hb4 = 0.f, hb5 = 0.f, hb6 = 0.f, hb7 = 0.f;
      TRAIL_C(0) TRAIL_C(1) TRAIL_C(2) TRAIL_C(3)
      TRAIL_C(4) TRAIL_C(5) TRAIL_C(6) TRAIL_C(7)
      if (tx == 0) {
        float4 h0 = *(float4*)&rhs[ty8]; float4 h1 = *(float4*)&rhs[ty8 + 4];
        h0.x -= hr0; h0.y -= hr1; h0.z -= hr2; h0.w -= hr3;
        h1.x -= hr4; h1.y -= hr5; h1.z -= hr6; h1.w -= hr7;
        *(float4*)&rhs[ty8] = h0; *(float4*)&rhs[ty8 + 4] = h1;
      }
      if (tx == 1) {
        float4 h0 = *(float4*)&bcol[ty8]; float4 h1 = *(float4*)&bcol[ty8 + 4];
        h0.x -= hb0; h0.y -= hb1; h0.z -= hb2; h0.w -= hb3;
        h1.x -= hb4; h1.y -= hb5; h1.z -= hb6; h1.w -= hb7;
        *(float4*)&bcol[ty8] = h0; *(float4*)&bcol[ty8 + 4] = h1;
      }
    }
  }
  __syncthreads();

  // ------- phase C: panel back-substitution (readlane, 2 barriers/panel) ----
  if (t == 0) betaL[ND] = rhs[ND] / bcol[ND];
  if (t < ND) { sp0[t] = 0.f; sp1[t] = 0.f; }
  __syncthreads();
  if (t < ND) rhs[t] = fmaf(-bcol[t], betaL[ND], rhs[t]);
  __syncthreads();
#pragma unroll 1
  for (int p = 15; p >= 0; --p) {
    const int p8 = p * 8;
    const bool hi = (p >= 8);
    const int ol = hi ? ((p - 8) << 1) : (p << 1);
    const int txo0 = ol, txo1 = ol + 1;
    if (ty == p) {
      asm volatile("s_waitcnt lgkmcnt(0)" ::: "memory");
      const float4 rq0 = *(const float4*)&rhs[p8];
      const float4 rq1 = *(const float4*)&rhs[p8 + 4];
      const float4 sq0 = *(const float4*)&sp0[p8];
      const float4 sq1 = *(const float4*)&sp0[p8 + 4];
      const float4 uq0 = *(const float4*)&sp1[p8];
      const float4 uq1 = *(const float4*)&sp1[p8 + 4];
      const float4 dq0 = *(const float4*)&pdiag[p8];
      const float4 dq1 = *(const float4*)&pdiag[p8 + 4];
      float rh0 = rq0.x - sq0.x - uq0.x, rh1 = rq0.y - sq0.y - uq0.y;
      float rh2 = rq0.z - sq0.z - uq0.z, rh3 = rq0.w - sq0.w - uq0.w;
      float rh4 = rq1.x - sq1.x - uq1.x, rh5 = rq1.y - sq1.y - uq1.y;
      float rh6 = rq1.z - sq1.z - uq1.z, rh7 = rq1.w - sq1.w - uq1.w;
      const float pd0 = dq0.x, pd1 = dq0.y, pd2 = dq0.z, pd3 = dq0.w;
      const float pd4 = dq1.x, pd5 = dq1.y, pd6 = dq1.z, pd7 = dq1.w;
      const int lsrc0 = ((p & 3) << 4) + ol;
      const int lsrc1 = lsrc0 + 1;
      float be0, be1, be2, be3, be4, be5, be6, be7;
      if (p < 8) {
        PC_S(7, PC_U(0,3,lsrc1,be7) PC_U(1,3,lsrc1,be7) PC_U(2,3,lsrc1,be7) PC_U(3,3,lsrc1,be7) PC_U(4,3,lsrc1,be7) PC_U(5,3,lsrc1,be7) PC_U(6,3,lsrc1,be7))
        PC_S(6, PC_U(0,2,lsrc1,be6) PC_U(1,2,lsrc1,be6) PC_U(2,2,lsrc1,be6) PC_U(3,2,lsrc1,be6) PC_U(4,2,lsrc1,be6) PC_U(5,2,lsrc1,be6))
        PC_S(5, PC_U(0,1,lsrc1,be5) PC_U(1,1,lsrc1,be5) PC_U(2,1,lsrc1,be5) PC_U(3,1,lsrc1,be5) PC_U(4,1,lsrc1,be5))
        PC_S(4, PC_U(0,0,lsrc1,be4) PC_U(1,0,lsrc1,be4) PC_U(2,0,lsrc1,be4) PC_U(3,0,lsrc1,be4))
        PC_S(3, PC_U(0,3,lsrc0,be3) PC_U(1,3,lsrc0,be3) PC_U(2,3,lsrc0,be3))
        PC_S(2, PC_U(0,2,lsrc0,be2) PC_U(1,2,lsrc0,be2))
        PC_S(1, PC_U(0,1,lsrc0,be1))
        PC_S(0, )
      } else {
        PC_S(7, PC_U(0,7,lsrc1,be7) PC_U(1,7,lsrc1,be7) PC_U(2,7,lsrc1,be7) PC_U(3,7,lsrc1,be7) PC_U(4,7,lsrc1,be7) PC_U(5,7,lsrc1,be7) PC_U(6,7,lsrc1,be7))
        PC_S(6, PC_U(0,6,lsrc1,be6) PC_U(1,6,lsrc1,be6) PC_U(2,6,lsrc1,be6) PC_U(3,6,lsrc1,be6) PC_U(4,6,lsrc1,be6) PC_U(5,6,lsrc1,be6))
        PC_S(5, PC_U(0,5,lsrc1,be5) PC_U(1,5,lsrc1,be5) PC_U(2,5,lsrc1,be5) PC_U(3,5,lsrc1,be5) PC_U(4,5,lsrc1,be5))
        PC_S(4, PC_U(0,4,lsrc1,be4) PC_U(1,4,lsrc1,be4) PC_U(2,4,lsrc1,be4) PC_U(3,4,lsrc1,be4))
        PC_S(3, PC_U(0,7,lsrc0,be3) PC_U(1,7,lsrc0,be3) PC_U(2,7,lsrc0,be3))
        PC_S(2, PC_U(0,6,lsrc0,be2) PC_U(1,6,lsrc0,be2))
        PC_S(1, PC_U(0,5,lsrc0,be1))
        PC_S(0, )
      }
      if (tx == 0) {
        *(float4*)&betaL[p8]     = make_float4(be0, be1, be2, be3);
        *(float4*)&betaL[p8 + 4] = make_float4(be4, be5, be6, be7);
      }
    }
    __syncthreads();
    if (ty < p && (tx == txo0 || tx == txo1)) {
      const bool second = (tx == txo1);
      const float4 beq = *(const float4*)&betaL[p8 + (second ? 4 : 0)];
      float* spd = second ? sp1 : sp0;
      const float be0 = beq.x, be1 = beq.y, be2 = beq.z, be3 = beq.w;
      PCT_ROW(0) PCT_ROW(1) PCT_ROW(2) PCT_ROW(3)
      PCT_ROW(4) PCT_ROW(5) PCT_ROW(6) PCT_ROW(7)
      float4 h0 = *(float4*)&spd[ty8]; float4 h1 = *(float4*)&spd[ty8 + 4];
      h0.x += ps0; h0.y += ps1; h0.z += ps2; h0.w += ps3;
      h1.x += ps4; h1.y += ps5; h1.z += ps6; h1.w += ps7;
      *(float4*)&spd[ty8] = h0; *(float4*)&spd[ty8 + 4] = h1;
    }
    __syncthreads();
  }
  if (t < NCOL) Beta[(size_t)b * BSTRIDE + t] = betaL[t];
}

// ---------------------------------------------------------------------------
// Kernel 2: BCE. 32 lanes/sample dot products -> LDS; then the transcendental
// BCE tail runs 64-wide on wave 0 (was serial on lane 0 of each group).
// One block = 64 consecutive samples = within ONE batch (256/64=4 blocks/batch).
// ---------------------------------------------------------------------------
__device__ inline float logsig(float v) {
  if (v >= 0.f) return -log1pf(expf(-v));
  return v - log1pf(expf(v));
}

__global__ __launch_bounds__(256)
void k_bce(const float* __restrict__ x, const float* __restrict__ noise,
           const float* __restrict__ W, const float* __restrict__ bptr,
           const float* __restrict__ Beta, float* __restrict__ partial) {
  const int t    = threadIdx.x;
  const int lane = t & 31;
  const int grp  = t >> 5;                       // 0..7
  const int bb   = blockIdx.x >> 2;              // batch (uniform per block)
  const size_t sbase = (size_t)blockIdx.x * 64;  // first flat sample id
  __shared__ float saw[64], sab[64];

  const float4 w4 = *((const float4*)W + lane);
  const float4 x4 = *((const float4*)x + (size_t)bb * 32 + lane);
  const float4 p4 = *((const float4*)(Beta + (size_t)bb * BSTRIDE) + lane);

  for (int it = 0; it < 8; ++it) {
    const size_t idx = sbase + grp * 8 + it;
    float4 n4 = *((const float4*)noise + idx * 32 + lane);
    float4 xl;
    xl.x = x4.x + STDDEV * n4.x;
    xl.y = x4.y + STDDEV * n4.y;
    xl.z = x4.z + STDDEV * n4.z;
    xl.w = x4.w + STDDEV * n4.w;
    float aw = xl.x * w4.x + xl.y * w4.y + xl.z * w4.z + xl.w * w4.w;
    float ab = xl.x * p4.x + xl.y * p4.y + xl.z * p4.z + xl.w * p4.w;
#pragma unroll
    for (int off = 16; off >= 1; off >>= 1) {
      aw += __shfl_xor(aw, off);
      ab += __shfl_xor(ab, off);
    }
    if (lane == 0) { saw[grp * 8 + it] = aw; sab[grp * 8 + it] = ab; }
  }
  __syncthreads();
  if (t < 64) {   // wave 0: 64 BCEs in parallel + reduce
    const float bscal = bptr[0];
    const float beta128 = Beta[(size_t)bb * BSTRIDE + 128];
    const float y    = 1.f / (1.f + expf(-(saw[t] + bscal)));
    const float ylin = sab[t] + beta128;
    float v = -(y * logsig(ylin) + (1.f - y) * logsig(-ylin));
#pragma unroll
    for (int off = 32; off >= 1; off >>= 1) v += __shfl_xor(v, off);
    if (t == 0) partial[blockIdx.x] = v;
  }
}

__global__ void k_final(const float* __restrict__ partial, float* __restrict__ out,
                        int n, float inv) {
  __shared__ float red[256];
  float s = 0.f;
  for (int i = threadIdx.x; i < n; i += 256) s += partial[i];
  red[threadIdx.x] = s;
  __syncthreads();
  for (int k = 128; k > 0; k >>= 1) {
    if (threadIdx.x < k) red[threadIdx.x] += red[threadIdx.x + k];
    __syncthreads();
  }
  if (threadIdx.x == 0) out[0] = red[0] * inv;
}

extern "C" void kernel_launch(void* const* d_in, const int* in_sizes, int n_in,
                              void* d_out, int out_size, void* d_ws, size_t ws_size,
                              hipStream_t stream) {
  const float* x     = (const float*)d_in[0];
  const float* noise = (const float*)d_in[1];
  const float* W     = (const float*)d_in[2];
  const float* bptr  = (const float*)d_in[3];
  float* out = (float*)d_out;

  float* Beta = (float*)d_ws;
  const size_t beta_bytes = (size_t)NB * BSTRIDE * sizeof(float);
  float* partial = (float*)((char*)d_ws + ((beta_bytes + 255) & ~(size_t)255));

  const int nblk2 = (NB * NS) / 64;  // 64 samples per block = 8192

  k_fit<<<NB, 256, 0, stream>>>(x, noise, W, bptr, Beta);
  k_bce<<<nblk2, 256, 0, stream>>>(x, noise, W, bptr, Beta, partial);
  k_final<<<1, 256, 0, stream>>>(partial, out, nblk2, 1.0f / (float)(NB * NS));
}

// Round 10
// 388.341 us; speedup vs baseline: 1.8841x; 1.8841x over previous
//
#include <hip/hip_runtime.h>
#include <math.h>

#define NB 2048        // batches
#define NS 256         // samples per batch
#define ND 128         // features
#define NCOL 129       // ND+1 (ones column)
#define LDA 132        // padded LDS row stride (floats)
#define TS 32          // samples per formation chunk (= one MFMA K step)
#define XTP 40         // XT pitch in shorts (32 samples + 8 pad -> 2-way banks)
#define BSTRIDE 132    // Beta row stride in workspace (floats)
#define STDDEV 0.1f

typedef __attribute__((ext_vector_type(8))) short bf16x8;
typedef __attribute__((ext_vector_type(4))) float f32x4;

__device__ inline unsigned short f32_to_bf16_rn(float f) {
  unsigned int u = __float_as_uint(f);
  unsigned int r = (u + 0x7FFFu + ((u >> 16) & 1u)) >> 16;
  return (unsigned short)r;
}
__device__ inline float bf16u_to_f32(unsigned short h) {
  return __uint_as_float(((unsigned int)h) << 16);
}
// wave-uniform lane read: v_readlane (no LDS-pipe traffic)
__device__ inline float rdlane(float v, int lane) {
  return __int_as_float(__builtin_amdgcn_readlane(__float_as_int(v), lane));
}

// 64 named elimination scalars: a<i>_<j>, row R_i = ty*8+i, cols
// C_j = tx*4+j (j<4) and 64+tx*4+(j-4) (j>=4).  Named scalars (not an
// array) so they can NEVER be demoted to scratch (rounds 2/3: acc[8][8]
// went to localMem -> 7-16 GB HBM scratch traffic).
#define FOR_ROW(F, i) F(i,0) F(i,1) F(i,2) F(i,3) F(i,4) F(i,5) F(i,6) F(i,7)
#define FOR_ALL(F) FOR_ROW(F,0) FOR_ROW(F,1) FOR_ROW(F,2) FOR_ROW(F,3) \
                   FOR_ROW(F,4) FOR_ROW(F,5) FOR_ROW(F,6) FOR_ROW(F,7)

#define ACC_DECL(i,j) float a##i##_##j = 0.f;
#define ACC_UPD(i,j)  a##i##_##j = fmaf(-m##i, rc##j, a##i##_##j);

// row cc -= m * row c (own 8 cols in registers)
#define ACC8(cc, c, m) \
  a##cc##_0 = fmaf(-(m), a##c##_0, a##cc##_0); \
  a##cc##_1 = fmaf(-(m), a##c##_1, a##cc##_1); \
  a##cc##_2 = fmaf(-(m), a##c##_2, a##cc##_2); \
  a##cc##_3 = fmaf(-(m), a##c##_3, a##cc##_3); \
  a##cc##_4 = fmaf(-(m), a##c##_4, a##cc##_4); \
  a##cc##_5 = fmaf(-(m), a##c##_5, a##cc##_5); \
  a##cc##_6 = fmaf(-(m), a##c##_6, a##cc##_6); \
  a##cc##_7 = fmaf(-(m), a##c##_7, a##cc##_7);

#define PF_U(c, cc) { const float m_ = pv##cc * pinv; \
  ACC8(cc, c, m_) \
  rh##cc = fmaf(-m_, rh##c, rh##cc); \
  bc##cc = fmaf(-m_, bc##c, bc##cc); }

#define PF_STEP(c, J0, J1, J2, J3, UPDS) { \
  const float pv0 = rdlane(a##c##_##J0, lsrc0); \
  const float pv1 = rdlane(a##c##_##J1, lsrc0); \
  const float pv2 = rdlane(a##c##_##J2, lsrc0); \
  const float pv3 = rdlane(a##c##_##J3, lsrc0); \
  const float pv4 = rdlane(a##c##_##J0, lsrc1); \
  const float pv5 = rdlane(a##c##_##J1, lsrc1); \
  const float pv6 = rdlane(a##c##_##J2, lsrc1); \
  const float pv7 = rdlane(a##c##_##J3, lsrc1); \
  const float pinv = 1.0f / pv##c; \
  if (tx == 3) pdiag[p8 + (c)] = pinv; \
  const float mb_ = bc##c * pinv; \
  cornb = fmaf(-mb_, bc##c, cornb); \
  cornr = fmaf(-mb_, rh##c, cornr); \
  UPDS }

#define PUBROW(c) \
  *(float4*)&rbp[(c) * LDA + txc0] = make_float4(a##c##_0, a##c##_1, a##c##_2, a##c##_3); \
  *(float4*)&rbp[(c) * LDA + txc1] = make_float4(a##c##_4, a##c##_5, a##c##_6, a##c##_7);

#define TRAIL_C(c) { \
  const float4 o0_ = *(const float4*)&rbp[(c) * LDA + ty8]; \
  const float4 o1_ = *(const float4*)&rbp[(c) * LDA + ty8 + 4]; \
  const float4 c0_ = *(const float4*)&rbp[(c) * LDA + txc0]; \
  const float4 c1_ = *(const float4*)&rbp[(c) * LDA + txc1]; \
  const float pk_ = pd[(c)]; \
  const float m0 = o0_.x*pk_, m1 = o0_.y*pk_, m2 = o0_.z*pk_, m3 = o0_.w*pk_; \
  const float m4 = o1_.x*pk_, m5 = o1_.y*pk_, m6 = o1_.z*pk_, m7 = o1_.w*pk_; \
  const float rc0 = c0_.x, rc1 = c0_.y, rc2 = c0_.z, rc3 = c0_.w; \
  const float rc4 = c1_.x, rc5 = c1_.y, rc6 = c1_.z, rc7 = c1_.w; \
  FOR_ALL(ACC_UPD) \
  hr0 = fmaf(m0, rp[(c)], hr0); hr1 = fmaf(m1, rp[(c)], hr1); \
  hr2 = fmaf(m2, rp[(c)], hr2); hr3 = fmaf(m3, rp[(c)], hr3); \
  hr4 = fmaf(m4, rp[(c)], hr4); hr5 = fmaf(m5, rp[(c)], hr5); \
  hr6 = fmaf(m6, rp[(c)], hr6); hr7 = fmaf(m7, rp[(c)], hr7); \
  hb0 = fmaf(m0, bp[(c)], hb0); hb1 = fmaf(m1, bp[(c)], hb1); \
  hb2 = fmaf(m2, bp[(c)], hb2); hb3 = fmaf(m3, bp[(c)], hb3); \
  hb4 = fmaf(m4, bp[(c)], hb4); hb5 = fmaf(m5, bp[(c)], hb5); \
  hb6 = fmaf(m6, bp[(c)], hb6); hb7 = fmaf(m7, bp[(c)], hb7); }

#define PC_U(cc, J, SRC, bev) { const float u_ = rdlane(a##cc##_##J, SRC); \
  rh##cc = fmaf(-u_, bev, rh##cc); }
#define PC_S(c, UPDS) { be##c = rh##c * pd##c; UPDS }

#define PCT_ROW(i) const float ps##i = hi \
  ? fmaf(a##i##_4, be0, fmaf(a##i##_5, be1, fmaf(a##i##_6, be2, a##i##_7 * be3))) \
  : fmaf(a##i##_0, be0, fmaf(a##i##_1, be1, fmaf(a##i##_2, be2, a##i##_3 * be3)));

// ---- MFMA formation macros ----
#define FOR_J(F) F(0) F(1) F(2) F(3) F(4) F(5) F(6) F(7)
#define CB_DECL(j) f32x4 cb0_##j = {0.f,0.f,0.f,0.f}; f32x4 cb1_##j = {0.f,0.f,0.f,0.f};

#define MF_J(j) { \
  const bf16x8 Bh = *(const bf16x8*)&XTh[(16*(j) + tx)*XTP + kq]; \
  const bf16x8 Bl = *(const bf16x8*)&XTl[(16*(j) + tx)*XTP + kq]; \
  cb0_##j = __builtin_amdgcn_mfma_f32_16x16x32_bf16(Ah0, Bh, cb0_##j, 0,0,0); \
  cb0_##j = __builtin_amdgcn_mfma_f32_16x16x32_bf16(Ah0, Bl, cb0_##j, 0,0,0); \
  cb0_##j = __builtin_amdgcn_mfma_f32_16x16x32_bf16(Al0, Bh, cb0_##j, 0,0,0); \
  cb1_##j = __builtin_amdgcn_mfma_f32_16x16x32_bf16(Ah1, Bh, cb1_##j, 0,0,0); \
  cb1_##j = __builtin_amdgcn_mfma_f32_16x16x32_bf16(Ah1, Bl, cb1_##j, 0,0,0); \
  cb1_##j = __builtin_amdgcn_mfma_f32_16x16x32_bf16(Al1, Bh, cb1_##j, 0,0,0); }

// transpose-convert one sample u (literal) of column d into frag vectors
#define TCONV(u, HV, LV, e) { \
  const float xf_ = sA[(sh + (u)) * LDA + d]; \
  const unsigned short hh_ = f32_to_bf16_rn(xf_); \
  const float hf_ = bf16u_to_f32(hh_); \
  const unsigned short ll_ = f32_to_bf16_rn(xf_ - hf_); \
  HV[e] = (short)hh_; LV[e] = (short)ll_; }

// stage one quarter of the chunk from prefetch register nv
#define STAGE_IT(it, nv) { \
  const int idx_ = t + (it) * 256; \
  const int s_ = idx_ >> 5, d4_ = idx_ & 31; \
  const float4 xq_ = *(const float4*)&xv[d4_ * 4]; \
  float4 xl_; \
  xl_.x = xq_.x + STDDEV * nv.x; \
  xl_.y = xq_.y + STDDEV * nv.y; \
  xl_.z = xq_.z + STDDEV * nv.z; \
  xl_.w = xq_.w + STDDEV * nv.w; \
  *(float4*)&sA[s_ * LDA + d4_ * 4] = xl_; }

// bridge: wave-local band write (C frag layout) / read (elimination layout)
#define BW_BJ(b, j) \
  myband[(16*(b) + q4 + 0)*132 + 16*(j) + tx] = cb##b##_##j[0]; \
  myband[(16*(b) + q4 + 1)*132 + 16*(j) + tx] = cb##b##_##j[1]; \
  myband[(16*(b) + q4 + 2)*132 + 16*(j) + tx] = cb##b##_##j[2]; \
  myband[(16*(b) + q4 + 3)*132 + 16*(j) + tx] = cb##b##_##j[3];
#define BW_ALL \
  BW_BJ(0,0) BW_BJ(0,1) BW_BJ(0,2) BW_BJ(0,3) BW_BJ(0,4) BW_BJ(0,5) BW_BJ(0,6) BW_BJ(0,7) \
  BW_BJ(1,0) BW_BJ(1,1) BW_BJ(1,2) BW_BJ(1,3) BW_BJ(1,4) BW_BJ(1,5) BW_BJ(1,6) BW_BJ(1,7)
#define BR_ROW(i) { \
  const float4 lo_ = *(const float4*)&myband[(q8 + (i))*132 + txc0]; \
  const float4 hi_ = *(const float4*)&myband[(q8 + (i))*132 + txc1]; \
  a##i##_0 = lo_.x; a##i##_1 = lo_.y; a##i##_2 = lo_.z; a##i##_3 = lo_.w; \
  a##i##_4 = hi_.x; a##i##_5 = hi_.y; a##i##_6 = hi_.z; a##i##_7 = hi_.w; }
#define BR_ALL \
  BR_ROW(0) BR_ROW(1) BR_ROW(2) BR_ROW(3) BR_ROW(4) BR_ROW(5) BR_ROW(6) BR_ROW(7)

// launch_bounds(256,2): 2 waves/EU (256-reg cap). (256,3) = 170-reg cap SPILLS
// (round-9: FETCH 131->408 MB, WRITE 1KB->0.94GB, k_fit 360->713us). The
// register floor is structural: 64 acc regs/lane (whole XtX resident at the
// bridge) + ~60 staging/working + 64 AGPR cb during phase A -> ~188 unified.
__global__ __launch_bounds__(256, 2)
void k_fit(const float* __restrict__ x, const float* __restrict__ noise,
           const float* __restrict__ W, const float* __restrict__ bptr,
           float* __restrict__ Beta) {
  // region0: phase A = sA f32 [32][132] | XTh u16 [128][40] | XTl u16 [128][40]
  //          bridge  = 2 bands f32 [32][132] (aliased, wave-pair serialized)
  //          phase B = rbuf (2112 f, aliased; region0 dead after bridge)
  //          phase C = sp0/sp1 (256 f, aliased, disjoint from rbuf)
  __shared__ __align__(16) float region0[9344];
  __shared__ __align__(16) float pdiag[NCOL + 3];
  __shared__ __align__(16) float bcol[NCOL + 3];     // border col; [128]=corner
  __shared__ __align__(16) float rhs[NCOL + 3];
  __shared__ __align__(16) float betaL[NCOL + 3];
  __shared__ __align__(16) float yt[TS];
  __shared__ __align__(16) float Wl[128];
  __shared__ __align__(16) float xv[128];

  float* sA = region0;                                   // 4224 floats
  unsigned short* XTh = (unsigned short*)(region0 + 4224);   // 5120 shorts
  unsigned short* XTl = (unsigned short*)(region0 + 4224 + 2560);
  float* band = region0;                                 // bridge alias
  float* rbuf = region0;                                 // phase-B alias [0,2112)
  float* sp0  = region0 + 2112;                          // phase-C alias
  float* sp1  = region0 + 2240;

  const int t  = threadIdx.x;
  const int b  = blockIdx.x;
  const int tx = t & 15;
  const int ty = t >> 4;
  const int wv = t >> 6;          // wave id 0..3
  const int txc0 = tx * 4;
  const int txc1 = 64 + tx * 4;
  const int ty8 = ty * 8;
  const int q4 = 4 * (ty & 3);    // C-frag row group
  const int q8 = 8 * (ty & 3);    // elimination band row base
  const int kq = 8 * (ty & 3);    // K offset within chunk (shorts)
  const float bscal = bptr[0];

  if (t < 128) { Wl[t] = W[t]; xv[t] = x[(size_t)b * ND + t]; }

  FOR_J(CB_DECL)                  // 16 named f32x4 MFMA accumulators
  float col_acc = 0.f, xty_acc = 0.f;

  const float* nbase = noise + (size_t)b * (NS * ND);

  // prefetch chunk 0 (T14: loads in flight across the staging barrier)
  float4 nv0, nv1, nv2, nv3;
  {
    const float4* src = (const float4*)nbase;
    nv0 = src[t]; nv1 = src[t + 256]; nv2 = src[t + 512]; nv3 = src[t + 768];
  }

  // ---------------- phase A: MFMA formation (8 chunks of 32) ----------------
  for (int s0 = 0; s0 < NS; s0 += TS) {
    __syncthreads();  // staging buffers free (covers Wl/xv on first iter)
    {   // write prefetched chunk -> sA (f32), xl = x + 0.1*noise
      STAGE_IT(0, nv0) STAGE_IT(1, nv1) STAGE_IT(2, nv2) STAGE_IT(3, nv3)
      if (t < TS) sA[t * LDA + ND] = 1.0f;   // ones column
    }
    if (s0 + TS < NS) {  // issue next chunk's loads; latency hides under chunk
      const float4* src = (const float4*)(nbase + (size_t)(s0 + TS) * ND);
      nv0 = src[t]; nv1 = src[t + 256]; nv2 = src[t + 512]; nv3 = src[t + 768];
    }
    __syncthreads();
    {   // transpose-convert: feature d = t>>1, sample half (t&1)*16 -> XT h/l
      const int d = t >> 1;
      const int sh = (t & 1) * 16;
      bf16x8 h0, h1, l0, l1;
      TCONV(0,h0,l0,0) TCONV(1,h0,l0,1) TCONV(2,h0,l0,2) TCONV(3,h0,l0,3)
      TCONV(4,h0,l0,4) TCONV(5,h0,l0,5) TCONV(6,h0,l0,6) TCONV(7,h0,l0,7)
      TCONV(8,h1,l1,0) TCONV(9,h1,l1,1) TCONV(10,h1,l1,2) TCONV(11,h1,l1,3)
      TCONV(12,h1,l1,4) TCONV(13,h1,l1,5) TCONV(14,h1,l1,6) TCONV(15,h1,l1,7)
      *(bf16x8*)&XTh[d * XTP + sh]     = h0;
      *(bf16x8*)&XTh[d * XTP + sh + 8] = h1;
      *(bf16x8*)&XTl[d * XTP + sh]     = l0;
      *(bf16x8*)&XTl[d * XTP + sh + 8] = l1;
    }
    {   // y = sigmoid(xl_feat . W + b), 8 threads/sample (f32-exact from sA)
      int sl = t >> 3, p = t & 7;
      float acw = 0.f;
#pragma unroll
      for (int d = 0; d < 4; ++d) {
        float4 a = *(const float4*)&sA[sl * LDA + p * 16 + d * 4];
        float4 w = *(const float4*)&Wl[p * 16 + d * 4];
        acw += a.x * w.x + a.y * w.y + a.z * w.z + a.w * w.w;
      }
      acw += __shfl_xor(acw, 1);
      acw += __shfl_xor(acw, 2);
      acw += __shfl_xor(acw, 4);
      if (p == 0) yt[sl] = 1.f / (1.f + expf(-(acw + bscal)));
    }
    __syncthreads();
    if (t < NCOL) {   // border col sums + Xty (f32-exact from sA)
      for (int s = 0; s < TS; ++s) {
        float v = sA[s * LDA + t];
        col_acc += v;
        xty_acc += yt[s] * v;
      }
    }
    {   // MFMA: wave wv owns rows 32wv..32wv+31; K = this chunk (32 samples)
      const bf16x8 Ah0 = *(const bf16x8*)&XTh[(32*wv + tx)*XTP + kq];
      const bf16x8 Al0 = *(const bf16x8*)&XTl[(32*wv + tx)*XTP + kq];
      const bf16x8 Ah1 = *(const bf16x8*)&XTh[(32*wv + 16 + tx)*XTP + kq];
      const bf16x8 Al1 = *(const bf16x8*)&XTl[(32*wv + 16 + tx)*XTP + kq];
      MF_J(0) MF_J(1) MF_J(2) MF_J(3) MF_J(4) MF_J(5) MF_J(6) MF_J(7)
    }
  }
  if (t < NCOL) { bcol[t] = col_acc; rhs[t] = xty_acc; }  // corner=256 natural
  __syncthreads();   // all XT reads done; region0 becomes bridge bands

  // ---- bridge: C fragments -> named elimination scalars (intra-wave) ----
  FOR_ALL(ACC_DECL)
  {
    float* myband = band + (wv & 1) * 4224;
    if (wv < 2) {
      BW_ALL
      asm volatile("s_waitcnt lgkmcnt(0)" ::: "memory");
      BR_ALL
      asm volatile("s_waitcnt lgkmcnt(0)" ::: "memory");
    }
    __syncthreads();
    if (wv >= 2) {
      BW_ALL
      asm volatile("s_waitcnt lgkmcnt(0)" ::: "memory");
      BR_ALL
      asm volatile("s_waitcnt lgkmcnt(0)" ::: "memory");
    }
    __syncthreads();   // bridge done; region0 free for rbuf/sp aliases
  }

  // ------- phase B: panel elimination (readlane factorization) --------------
#pragma unroll 1
  for (int p = 0; p < 16; ++p) {
    const int p8 = p * 8;
    const int ol = (p < 8) ? (p << 1) : ((p - 8) << 1);
    float* rbp = &rbuf[(p & 1) * (8 * LDA)];
    if (ty == p) {
      asm volatile("s_waitcnt lgkmcnt(0)" ::: "memory");
      const float4 rq0 = *(const float4*)&rhs[p8];
      const float4 rq1 = *(const float4*)&rhs[p8 + 4];
      const float4 bq0 = *(const float4*)&bcol[p8];
      const float4 bq1 = *(const float4*)&bcol[p8 + 4];
      float rh0 = rq0.x, rh1 = rq0.y, rh2 = rq0.z, rh3 = rq0.w;
      float rh4 = rq1.x, rh5 = rq1.y, rh6 = rq1.z, rh7 = rq1.w;
      float bc0 = bq0.x, bc1 = bq0.y, bc2 = bq0.z, bc3 = bq0.w;
      float bc4 = bq1.x, bc5 = bq1.y, bc6 = bq1.z, bc7 = bq1.w;
      float cornr = rhs[ND], cornb = bcol[ND];
      const int lsrc0 = ((p & 3) << 4) + ol;
      const int lsrc1 = lsrc0 + 1;
      if (p < 8) {
        PF_STEP(0, 0,1,2,3, PF_U(0,1) PF_U(0,2) PF_U(0,3) PF_U(0,4) PF_U(0,5) PF_U(0,6) PF_U(0,7))
        PF_STEP(1, 0,1,2,3, PF_U(1,2) PF_U(1,3) PF_U(1,4) PF_U(1,5) PF_U(1,6) PF_U(1,7))
        PF_STEP(2, 0,1,2,3, PF_U(2,3) PF_U(2,4) PF_U(2,5) PF_U(2,6) PF_U(2,7))
        PF_STEP(3, 0,1,2,3, PF_U(3,4) PF_U(3,5) PF_U(3,6) PF_U(3,7))
        PF_STEP(4, 0,1,2,3, PF_U(4,5) PF_U(4,6) PF_U(4,7))
        PF_STEP(5, 0,1,2,3, PF_U(5,6) PF_U(5,7))
        PF_STEP(6, 0,1,2,3, PF_U(6,7))
        PF_STEP(7, 0,1,2,3, )
      } else {
        PF_STEP(0, 4,5,6,7, PF_U(0,1) PF_U(0,2) PF_U(0,3) PF_U(0,4) PF_U(0,5) PF_U(0,6) PF_U(0,7))
        PF_STEP(1, 4,5,6,7, PF_U(1,2) PF_U(1,3) PF_U(1,4) PF_U(1,5) PF_U(1,6) PF_U(1,7))
        PF_STEP(2, 4,5,6,7, PF_U(2,3) PF_U(2,4) PF_U(2,5) PF_U(2,6) PF_U(2,7))
        PF_STEP(3, 4,5,6,7, PF_U(3,4) PF_U(3,5) PF_U(3,6) PF_U(3,7))
        PF_STEP(4, 4,5,6,7, PF_U(4,5) PF_U(4,6) PF_U(4,7))
        PF_STEP(5, 4,5,6,7, PF_U(5,6) PF_U(5,7))
        PF_STEP(6, 4,5,6,7, PF_U(6,7))
        PF_STEP(7, 4,5,6,7, )
      }
      PUBROW(0) PUBROW(1) PUBROW(2) PUBROW(3)
      PUBROW(4) PUBROW(5) PUBROW(6) PUBROW(7)
      if (tx == 0) {
        *(float4*)&rhs[p8]     = make_float4(rh0, rh1, rh2, rh3);
        *(float4*)&rhs[p8 + 4] = make_float4(rh4, rh5, rh6, rh7);
      }
      if (tx == 1) {
        *(float4*)&bcol[p8]     = make_float4(bc0, bc1, bc2, bc3);
        *(float4*)&bcol[p8 + 4] = make_float4(bc4, bc5, bc6, bc7);
      }
      if (tx == 2) { rhs[ND] = cornr; bcol[ND] = cornb; }
    }
    __syncthreads();
    if (ty > p) {
      const float4 d0_ = *(const float4*)&pdiag[p8];
      const float4 d1_ = *(const float4*)&pdiag[p8 + 4];
      const float4 rq0_ = *(const float4*)&rhs[p8];
      const float4 rq1_ = *(const float4*)&rhs[p8 + 4];
      const float4 bq0_ = *(const float4*)&bcol[p8];
      const float4 bq1_ = *(const float4*)&bcol[p8 + 4];
      const float pd[8] = {d0_.x, d0_.y, d0_.z, d0_.w, d1_.x, d1_.y, d1_.z, d1_.w};
      const float rp[8] = {rq0_.x, rq0_.y, rq0_.z, rq0_.w, rq1_.x, rq1_.y, rq1_.z, rq1_.w};
      const float bp[8] = {bq0_.x, bq0_.y, bq0_.z, bq0_.w, bq1_.x, bq1_.y, bq1_.z, bq1_.w};
      float hr0 = 0.f, hr1 = 0.f, hr2 = 0.f, hr3 = 0.f;
      float hr4 = 0.f, hr5 = 0.f, hr6 = 0.f, hr7 = 0.f;
      float hb0 = 0.f, hb1 = 0.f, hb2 = 0.f, hb3 = 0.f;
      float hb4 = 0.f, hb5 = 0.f, hb6 = 0.f, hb7 = 0.f;
      TRAIL_C(0) TRAIL_C(1) TRAIL_C(2) TRAIL_C(3)
      TRAIL_C(4) TRAIL_C(5) TRAIL_C(6) TRAIL_C(7)
      if (tx == 0) {
        float4 h0 = *(float4*)&rhs[ty8]; float4 h1 = *(float4*)&rhs[ty8 + 4];
        h0.x -= hr0; h0.y -= hr1; h0.z -= hr2; h0.w -= hr3;
        h1.x -= hr4; h1.y -= hr5; h1.z -= hr6; h1.w -= hr7;
        *(float4*)&rhs[ty8] = h0; *(float4*)&rhs[ty8 + 4] = h1;
      }
      if (tx == 1) {
        float4 h0 = *(float4*)&bcol[ty8]; float4 h1 = *(float4*)&bcol[ty8 + 4];
        h0.x -= hb0; h0.y -= hb1; h0.z -= hb2; h0.w -= hb3;
        h1.x -= hb4; h1.y -= hb5; h1.z -= hb6; h1.w -= hb7;
        *(float4*)&bcol[ty8] = h0; *(float4*)&bcol[ty8 + 4] = h1;
      }
    }
  }
  __syncthreads();

  // ------- phase C: panel back-substitution (readlane, 2 barriers/panel) ----
  if (t == 0) betaL[ND] = rhs[ND] / bcol[ND];
  if (t < ND) { sp0[t] = 0.f; sp1[t] = 0.f; }
  __syncthreads();
  if (t < ND) rhs[t] = fmaf(-bcol[t], betaL[ND], rhs[t]);
  __syncthreads();
#pragma unroll 1
  for (int p = 15; p >= 0; --p) {
    const int p8 = p * 8;
    const bool hi = (p >= 8);
    const int ol = hi ? ((p - 8) << 1) : (p << 1);
    const int txo0 = ol, txo1 = ol + 1;
    if (ty == p) {
      asm volatile("s_waitcnt lgkmcnt(0)" ::: "memory");
      const float4 rq0 = *(const float4*)&rhs[p8];
      const float4 rq1 = *(const float4*)&rhs[p8 + 4];
      const float4 sq0 = *(const float4*)&sp0[p8];
      const float4 sq1 = *(const float4*)&sp0[p8 + 4];
      const float4 uq0 = *(const float4*)&sp1[p8];
      const float4 uq1 = *(const float4*)&sp1[p8 + 4];
      const float4 dq0 = *(const float4*)&pdiag[p8];
      const float4 dq1 = *(const float4*)&pdiag[p8 + 4];
      float rh0 = rq0.x - sq0.x - uq0.x, rh1 = rq0.y - sq0.y - uq0.y;
      float rh2 = rq0.z - sq0.z - uq0.z, rh3 = rq0.w - sq0.w - uq0.w;
      float rh4 = rq1.x - sq1.x - uq1.x, rh5 = rq1.y - sq1.y - uq1.y;
      float rh6 = rq1.z - sq1.z - uq1.z, rh7 = rq1.w - sq1.w - uq1.w;
      const float pd0 = dq0.x, pd1 = dq0.y, pd2 = dq0.z, pd3 = dq0.w;
      const float pd4 = dq1.x, pd5 = dq1.y, pd6 = dq1.z, pd7 = dq1.w;
      const int lsrc0 = ((p & 3) << 4) + ol;
      const int lsrc1 = lsrc0 + 1;
      float be0, be1, be2, be3, be4, be5, be6, be7;
      if (p < 8) {
        PC_S(7, PC_U(0,3,lsrc1,be7) PC_U(1,3,lsrc1,be7) PC_U(2,3,lsrc1,be7) PC_U(3,3,lsrc1,be7) PC_U(4,3,lsrc1,be7) PC_U(5,3,lsrc1,be7) PC_U(6,3,lsrc1,be7))
        PC_S(6, PC_U(0,2,lsrc1,be6) PC_U(1,2,lsrc1,be6) PC_U(2,2,lsrc1,be6) PC_U(3,2,lsrc1,be6) PC_U(4,2,lsrc1,be6) PC_U(5,2,lsrc1,be6))
        PC_S(5, PC_U(0,1,lsrc1,be5) PC_U(1,1,lsrc1,be5) PC_U(2,1,lsrc1,be5) PC_U(3,1,lsrc1,be5) PC_U(4,1,lsrc1,be5))
        PC_S(4, PC_U(0,0,lsrc1,be4) PC_U(1,0,lsrc1,be4) PC_U(2,0,lsrc1,be4) PC_U(3,0,lsrc1,be4))
        PC_S(3, PC_U(0,3,lsrc0,be3) PC_U(1,3,lsrc0,be3) PC_U(2,3,lsrc0,be3))
        PC_S(2, PC_U(0,2,lsrc0,be2) PC_U(1,2,lsrc0,be2))
        PC_S(1, PC_U(0,1,lsrc0,be1))
        PC_S(0, )
      } else {
        PC_S(7, PC_U(0,7,lsrc1,be7) PC_U(1,7,lsrc1,be7) PC_U(2,7,lsrc1,be7) PC_U(3,7,lsrc1,be7) PC_U(4,7,lsrc1,be7) PC_U(5,7,lsrc1,be7) PC_U(6,7,lsrc1,be7))
        PC_S(6, PC_U(0,6,lsrc1,be6) PC_U(1,6,lsrc1,be6) PC_U(2,6,lsrc1,be6) PC_U(3,6,lsrc1,be6) PC_U(4,6,lsrc1,be6) PC_U(5,6,lsrc1,be6))
        PC_S(5, PC_U(0,5,lsrc1,be5) PC_U(1,5,lsrc1,be5) PC_U(2,5,lsrc1,be5) PC_U(3,5,lsrc1,be5) PC_U(4,5,lsrc1,be5))
        PC_S(4, PC_U(0,4,lsrc1,be4) PC_U(1,4,lsrc1,be4) PC_U(2,4,lsrc1,be4) PC_U(3,4,lsrc1,be4))
        PC_S(3, PC_U(0,7,lsrc0,be3) PC_U(1,7,lsrc0,be3) PC_U(2,7,lsrc0,be3))
        PC_S(2, PC_U(0,6,lsrc0,be2) PC_U(1,6,lsrc0,be2))
        PC_S(1, PC_U(0,5,lsrc0,be1))
        PC_S(0, )
      }
      if (tx == 0) {
        *(float4*)&betaL[p8]     = make_float4(be0, be1, be2, be3);
        *(float4*)&betaL[p8 + 4] = make_float4(be4, be5, be6, be7);
      }
    }
    __syncthreads();
    if (ty < p && (tx == txo0 || tx == txo1)) {
      const bool second = (tx == txo1);
      const float4 beq = *(const float4*)&betaL[p8 + (second ? 4 : 0)];
      float* spd = second ? sp1 : sp0;
      const float be0 = beq.x, be1 = beq.y, be2 = beq.z, be3 = beq.w;
      PCT_ROW(0) PCT_ROW(1) PCT_ROW(2) PCT_ROW(3)
      PCT_ROW(4) PCT_ROW(5) PCT_ROW(6) PCT_ROW(7)
      float4 h0 = *(float4*)&spd[ty8]; float4 h1 = *(float4*)&spd[ty8 + 4];
      h0.x += ps0; h0.y += ps1; h0.z += ps2; h0.w += ps3;
      h1.x += ps4; h1.y += ps5; h1.z += ps6; h1.w += ps7;
      *(float4*)&spd[ty8] = h0; *(float4*)&spd[ty8 + 4] = h1;
    }
    __syncthreads();
  }
  if (t < NCOL) Beta[(size_t)b * BSTRIDE + t] = betaL[t];
}

// ---------------------------------------------------------------------------
// Kernel 2: BCE. 32 lanes/sample dot products -> LDS; then the transcendental
// BCE tail runs 64-wide on wave 0 (was serial on lane 0 of each group).
// One block = 64 consecutive samples = within ONE batch (256/64=4 blocks/batch).
// ---------------------------------------------------------------------------
__device__ inline float logsig(float v) {
  if (v >= 0.f) return -log1pf(expf(-v));
  return v - log1pf(expf(v));
}

__global__ __launch_bounds__(256)
void k_bce(const float* __restrict__ x, const float* __restrict__ noise,
           const float* __restrict__ W, const float* __restrict__ bptr,
           const float* __restrict__ Beta, float* __restrict__ partial) {
  const int t    = threadIdx.x;
  const int lane = t & 31;
  const int grp  = t >> 5;                       // 0..7
  const int bb   = blockIdx.x >> 2;              // batch (uniform per block)
  const size_t sbase = (size_t)blockIdx.x * 64;  // first flat sample id
  __shared__ float saw[64], sab[64];

  const float4 w4 = *((const float4*)W + lane);
  const float4 x4 = *((const float4*)x + (size_t)bb * 32 + lane);
  const float4 p4 = *((const float4*)(Beta + (size_t)bb * BSTRIDE) + lane);

  for (int it = 0; it < 8; ++it) {
    const size_t idx = sbase + grp * 8 + it;
    float4 n4 = *((const float4*)noise + idx * 32 + lane);
    float4 xl;
    xl.x = x4.x + STDDEV * n4.x;
    xl.y = x4.y + STDDEV * n4.y;
    xl.z = x4.z + STDDEV * n4.z;
    xl.w = x4.w + STDDEV * n4.w;
    float aw = xl.x * w4.x + xl.y * w4.y + xl.z * w4.z + xl.w * w4.w;
    float ab = xl.x * p4.x + xl.y * p4.y + xl.z * p4.z + xl.w * p4.w;
#pragma unroll
    for (int off = 16; off >= 1; off >>= 1) {
      aw += __shfl_xor(aw, off);
      ab += __shfl_xor(ab, off);
    }
    if (lane == 0) { saw[grp * 8 + it] = aw; sab[grp * 8 + it] = ab; }
  }
  __syncthreads();
  if (t < 64) {   // wave 0: 64 BCEs in parallel + reduce
    const float bscal = bptr[0];
    const float beta128 = Beta[(size_t)bb * BSTRIDE + 128];
    const float y    = 1.f / (1.f + expf(-(saw[t] + bscal)));
    const float ylin = sab[t] + beta128;
    float v = -(y * logsig(ylin) + (1.f - y) * logsig(-ylin));
#pragma unroll
    for (int off = 32; off >= 1; off >>= 1) v += __shfl_xor(v, off);
    if (t == 0) partial[blockIdx.x] = v;
  }
}

__global__ void k_final(const float* __restrict__ partial, float* __restrict__ out,
                        int n, float inv) {
  __shared__ float red[256];
  float s = 0.f;
  for (int i = threadIdx.x; i < n; i += 256) s += partial[i];
  red[threadIdx.x] = s;
  __syncthreads();
  for (int k = 128; k > 0; k >>= 1) {
    if (threadIdx.x < k) red[threadIdx.x] += red[threadIdx.x + k];
    __syncthreads();
  }
  if (threadIdx.x == 0) out[0] = red[0] * inv;
}

extern "C" void kernel_launch(void* const* d_in, const int* in_sizes, int n_in,
                              void* d_out, int out_size, void* d_ws, size_t ws_size,
                              hipStream_t stream) {
  const float* x     = (const float*)d_in[0];
  const float* noise = (const float*)d_in[1];
  const float* W     = (const float*)d_in[2];
  const float* bptr  = (const float*)d_in[3];
  float* out = (float*)d_out;

  float* Beta = (float*)d_ws;
  const size_t beta_bytes = (size_t)NB * BSTRIDE * sizeof(float);
  float* partial = (float*)((char*)d_ws + ((beta_bytes + 255) & ~(size_t)255));

  const int nblk2 = (NB * NS) / 64;  // 64 samples per block = 8192

  k_fit<<<NB, 256, 0, stream>>>(x, noise, W, bptr, Beta);
  k_bce<<<nblk2, 256, 0, stream>>>(x, noise, W, bptr, Beta, partial);
  k_final<<<1, 256, 0, stream>>>(partial, out, nblk2, 1.0f / (float)(NB * NS));
}